// Round 1
// baseline (82.360 us; speedup 1.0000x reference)
//
#include <hip/hip_runtime.h>
#include <hip/hip_bf16.h>

#define NN 7
#define HH 16
#define RR 64
#define CC 8
#define NBINS (NN * RR * NN)   // 3136

// ---------------------------------------------------------------------------
// Kernel 1: histogram edges into (dst, rel, src) bins.
// Integer atomics -> exactly deterministic.
// ---------------------------------------------------------------------------
__global__ __launch_bounds__(256) void rgcn_hist(
    const int* __restrict__ src, const int* __restrict__ dst,
    const int* __restrict__ et, int E, int* __restrict__ gbins) {
    __shared__ int bins[NBINS];
    for (int i = threadIdx.x; i < NBINS; i += blockDim.x) bins[i] = 0;
    __syncthreads();

    const int tid = blockIdx.x * blockDim.x + threadIdx.x;
    const int stride = gridDim.x * blockDim.x;
    const int E4 = E >> 2;  // vectorized portion
    const int4* s4 = reinterpret_cast<const int4*>(src);
    const int4* d4 = reinterpret_cast<const int4*>(dst);
    const int4* t4 = reinterpret_cast<const int4*>(et);

    for (int i = tid; i < E4; i += stride) {
        int4 s = s4[i];
        int4 d = d4[i];
        int4 t = t4[i];
        atomicAdd(&bins[d.x * (RR * NN) + t.x * NN + s.x], 1);
        atomicAdd(&bins[d.y * (RR * NN) + t.y * NN + s.y], 1);
        atomicAdd(&bins[d.z * (RR * NN) + t.z * NN + s.z], 1);
        atomicAdd(&bins[d.w * (RR * NN) + t.w * NN + s.w], 1);
    }
    // scalar tail (E not multiple of 4)
    for (int e = (E4 << 2) + tid; e < E; e += stride) {
        atomicAdd(&bins[dst[e] * (RR * NN) + et[e] * NN + src[e]], 1);
    }

    __syncthreads();
    for (int i = threadIdx.x; i < NBINS; i += blockDim.x) {
        int v = bins[i];
        if (v) atomicAdd(&gbins[i], v);
    }
}

// ---------------------------------------------------------------------------
// Kernel 2: everything else, single block. ~130 KFLOP total.
// ---------------------------------------------------------------------------
__global__ __launch_bounds__(256) void rgcn_finish(
    const int* __restrict__ gbins,
    const float* __restrict__ W1,    // [R][N][H]
    const float* __restrict__ root1, // [N][H]
    const float* __restrict__ b1,    // [H]
    const float* __restrict__ W2,    // [R][H][C]
    const float* __restrict__ root2, // [H][C]
    const float* __restrict__ b2,    // [C]
    float* __restrict__ out) {       // [N][C]
    __shared__ int   craw[NN][RR][NN];
    __shared__ float cntf[NN][RR][NN];  // cnt * (1/max(tot,1))
    __shared__ float h[NN][HH];
    __shared__ float hr[NN][RR][CC];    // hr[src][r][c]
    __shared__ float o[NN][CC];

    const int t = threadIdx.x;
    for (int i = t; i < NBINS; i += blockDim.x)
        reinterpret_cast<int*>(craw)[i] = gbins[i];
    __syncthreads();

    // per-(dst, rel) totals -> normalized counts
    for (int i = t; i < NN * RR; i += blockDim.x) {
        int n = i / RR, r = i % RR;
        int tot = 0;
        for (int s = 0; s < NN; ++s) tot += craw[n][r][s];
        float inv = 1.0f / (float)(tot > 0 ? tot : 1);
        for (int s = 0; s < NN; ++s) cntf[n][r][s] = (float)craw[n][r][s] * inv;
    }
    __syncthreads();

    // layer 1: h[n][j] = relu(root1 + b1 + sum_{r,s} cntf * W1[r][s][j])
    for (int i = t; i < NN * HH; i += blockDim.x) {
        int n = i / HH, j = i % HH;
        float acc = root1[n * HH + j] + b1[j];
        for (int r = 0; r < RR; ++r)
            for (int s = 0; s < NN; ++s)
                acc = fmaf(cntf[n][r][s], W1[(r * NN + s) * HH + j], acc);
        h[n][j] = fmaxf(acc, 0.0f);
    }
    __syncthreads();

    // hr[s][r][c] = sum_j h[s][j] * W2[r][j][c]
    for (int i = t; i < NN * RR * CC; i += blockDim.x) {
        int s = i / (RR * CC);
        int rem = i % (RR * CC);
        int r = rem / CC, c = rem % CC;
        float acc = 0.0f;
        for (int j = 0; j < HH; ++j)
            acc = fmaf(h[s][j], W2[(r * HH + j) * CC + c], acc);
        hr[s][r][c] = acc;
    }
    __syncthreads();

    // layer 2: out[n][c] = b2 + h[n]@root2 + sum_{r,s} cntf[n][r][s]*hr[s][r][c]
    for (int i = t; i < NN * CC; i += blockDim.x) {
        int n = i / CC, c = i % CC;
        float acc = b2[c];
        for (int j = 0; j < HH; ++j)
            acc = fmaf(h[n][j], root2[j * CC + c], acc);
        for (int r = 0; r < RR; ++r)
            for (int s = 0; s < NN; ++s)
                acc = fmaf(cntf[n][r][s], hr[s][r][c], acc);
        o[n][c] = acc;
    }
    __syncthreads();

    // row-wise log_softmax, one thread per node
    if (t < NN) {
        float m = -1e30f;
        for (int c = 0; c < CC; ++c) m = fmaxf(m, o[t][c]);
        float sum = 0.0f;
        for (int c = 0; c < CC; ++c) sum += expf(o[t][c] - m);
        float lse = m + logf(sum);
        for (int c = 0; c < CC; ++c) out[t * CC + c] = o[t][c] - lse;
    }
}

extern "C" void kernel_launch(void* const* d_in, const int* in_sizes, int n_in,
                              void* d_out, int out_size, void* d_ws, size_t ws_size,
                              hipStream_t stream) {
    // input order: x, edge_index, edge_type, W1, root1, b1, W2, root2, b2
    const int* edge_index = (const int*)d_in[1];
    const int* edge_type  = (const int*)d_in[2];
    const float* W1    = (const float*)d_in[3];
    const float* root1 = (const float*)d_in[4];
    const float* b1    = (const float*)d_in[5];
    const float* W2    = (const float*)d_in[6];
    const float* root2 = (const float*)d_in[7];
    const float* b2    = (const float*)d_in[8];
    float* out = (float*)d_out;

    const int E = in_sizes[2];              // num edges
    const int* src = edge_index;            // edge_index[0]
    const int* dst = edge_index + E;        // edge_index[1]

    int* gbins = (int*)d_ws;
    hipMemsetAsync(gbins, 0, NBINS * sizeof(int), stream);

    const int block = 256;
    const int grid = 2048;  // ~8 blocks/CU; grid-stride covers E
    rgcn_hist<<<grid, block, 0, stream>>>(src, dst, edge_type, E, gbins);
    rgcn_finish<<<1, 256, 0, stream>>>(gbins, W1, root1, b1, W2, root2, b2, out);
}

// Round 2
// 48.993 us; speedup vs baseline: 1.6810x; 1.6810x over previous
//
#include <hip/hip_runtime.h>
#include <hip/hip_bf16.h>

#define NN 7
#define HH 16
#define RR 64
#define CC 8
#define NBINS (NN * RR * NN)   // 3136

#define HIST_BLOCK 1024
#define HIST_GRID  512

// ---------------------------------------------------------------------------
// Kernel 1: histogram edges into (dst, rel, src) bins. Integer atomics ->
// exactly deterministic. Pipelined int4 loads; rotated global flush.
// ---------------------------------------------------------------------------
__global__ __launch_bounds__(HIST_BLOCK) void rgcn_hist(
    const int* __restrict__ src, const int* __restrict__ dst,
    const int* __restrict__ et, int E, int* __restrict__ gbins) {
    __shared__ int bins[NBINS];
    for (int i = threadIdx.x; i < NBINS; i += blockDim.x) bins[i] = 0;
    __syncthreads();

    const int tid = blockIdx.x * blockDim.x + threadIdx.x;
    const int stride = gridDim.x * blockDim.x;
    const int E4 = E >> 2;
    const int4* s4 = reinterpret_cast<const int4*>(src);
    const int4* d4 = reinterpret_cast<const int4*>(dst);
    const int4* t4 = reinterpret_cast<const int4*>(et);

    int i = tid;
    if (i < E4) {
        int4 s = s4[i], d = d4[i], t = t4[i];
        for (;;) {
            const int ni = i + stride;
            const bool more = ni < E4;
            int4 s2, d2, t2;
            if (more) { s2 = s4[ni]; d2 = d4[ni]; t2 = t4[ni]; }  // prefetch
            atomicAdd(&bins[d.x * (RR * NN) + t.x * NN + s.x], 1);
            atomicAdd(&bins[d.y * (RR * NN) + t.y * NN + s.y], 1);
            atomicAdd(&bins[d.z * (RR * NN) + t.z * NN + s.z], 1);
            atomicAdd(&bins[d.w * (RR * NN) + t.w * NN + s.w], 1);
            if (!more) break;
            s = s2; d = d2; t = t2; i = ni;
        }
    }
    // scalar tail (E not multiple of 4)
    for (int e = (E4 << 2) + tid; e < E; e += stride) {
        atomicAdd(&bins[dst[e] * (RR * NN) + et[e] * NN + src[e]], 1);
    }

    __syncthreads();
    // rotated flush: spread same-address atomic pressure across cachelines
    int rot = (blockIdx.x * 997) % NBINS;
    for (int i2 = threadIdx.x; i2 < NBINS; i2 += blockDim.x) {
        int idx = i2 + rot;
        if (idx >= NBINS) idx -= NBINS;
        int v = bins[idx];
        if (v) atomicAdd(&gbins[idx], v);
    }
}

// ---------------------------------------------------------------------------
// Kernel 2: everything else, single block of 512. W1/W2 staged into LDS.
// ---------------------------------------------------------------------------
__global__ __launch_bounds__(512) void rgcn_finish(
    const int* __restrict__ gbins,
    const float* __restrict__ W1,    // [R][N][H]
    const float* __restrict__ root1, // [N][H]
    const float* __restrict__ b1,    // [H]
    const float* __restrict__ W2,    // [R][H][C]
    const float* __restrict__ root2, // [H][C]
    const float* __restrict__ b2,    // [C]
    float* __restrict__ out) {       // [N][C]
    __shared__ int   craw[NN][RR][NN];
    __shared__ float cntf[NN][RR][NN];  // cnt * (1/max(tot,1))
    __shared__ float w1s[RR * NN * HH]; // 7168 floats
    __shared__ float w2s[RR * HH * CC]; // 8192 floats
    __shared__ float h[NN][HH];
    __shared__ float hr[NN][RR][CC];    // hr[src][r][c]
    __shared__ float o[NN][CC];

    const int t = threadIdx.x;
    // stage everything (coalesced), single barrier
    for (int i = t; i < NBINS; i += blockDim.x)
        reinterpret_cast<int*>(craw)[i] = gbins[i];
    const float4* W1v = reinterpret_cast<const float4*>(W1);
    for (int i = t; i < RR * NN * HH / 4; i += blockDim.x)
        reinterpret_cast<float4*>(w1s)[i] = W1v[i];
    const float4* W2v = reinterpret_cast<const float4*>(W2);
    for (int i = t; i < RR * HH * CC / 4; i += blockDim.x)
        reinterpret_cast<float4*>(w2s)[i] = W2v[i];
    __syncthreads();

    // per-(dst, rel) totals -> normalized counts
    for (int i = t; i < NN * RR; i += blockDim.x) {
        int n = i / RR, r = i % RR;
        int tot = 0;
        for (int s = 0; s < NN; ++s) tot += craw[n][r][s];
        float inv = 1.0f / (float)(tot > 0 ? tot : 1);
        for (int s = 0; s < NN; ++s) cntf[n][r][s] = (float)craw[n][r][s] * inv;
    }
    __syncthreads();

    // layer 1: h[n][j] = relu(root1 + b1 + sum_{r,s} cntf * W1[r][s][j])
    for (int i = t; i < NN * HH; i += blockDim.x) {
        int n = i / HH, j = i % HH;
        float acc = root1[n * HH + j] + b1[j];
        for (int r = 0; r < RR; ++r)
            for (int s = 0; s < NN; ++s)
                acc = fmaf(cntf[n][r][s], w1s[(r * NN + s) * HH + j], acc);
        h[n][j] = fmaxf(acc, 0.0f);
    }
    __syncthreads();

    // hr[s][r][c] = sum_j h[s][j] * W2[r][j][c]
    for (int i = t; i < NN * RR * CC; i += blockDim.x) {
        int s = i / (RR * CC);
        int rem = i % (RR * CC);
        int r = rem / CC, c = rem % CC;
        float acc = 0.0f;
        for (int j = 0; j < HH; ++j)
            acc = fmaf(h[s][j], w2s[(r * HH + j) * CC + c], acc);
        hr[s][r][c] = acc;
    }
    __syncthreads();

    // layer 2: out[n][c] = b2 + h[n]@root2 + sum_{r,s} cntf[n][r][s]*hr[s][r][c]
    for (int i = t; i < NN * CC; i += blockDim.x) {
        int n = i / CC, c = i % CC;
        float acc = b2[c];
        for (int j = 0; j < HH; ++j)
            acc = fmaf(h[n][j], root2[j * CC + c], acc);
        for (int r = 0; r < RR; ++r)
            for (int s = 0; s < NN; ++s)
                acc = fmaf(cntf[n][r][s], hr[s][r][c], acc);
        o[n][c] = acc;
    }
    __syncthreads();

    // row-wise log_softmax, one thread per node
    if (t < NN) {
        float m = -1e30f;
        for (int c = 0; c < CC; ++c) m = fmaxf(m, o[t][c]);
        float sum = 0.0f;
        for (int c = 0; c < CC; ++c) sum += __expf(o[t][c] - m);
        float lse = m + __logf(sum);
        for (int c = 0; c < CC; ++c) out[t * CC + c] = o[t][c] - lse;
    }
}

extern "C" void kernel_launch(void* const* d_in, const int* in_sizes, int n_in,
                              void* d_out, int out_size, void* d_ws, size_t ws_size,
                              hipStream_t stream) {
    // input order: x, edge_index, edge_type, W1, root1, b1, W2, root2, b2
    const int* edge_index = (const int*)d_in[1];
    const int* edge_type  = (const int*)d_in[2];
    const float* W1    = (const float*)d_in[3];
    const float* root1 = (const float*)d_in[4];
    const float* b1    = (const float*)d_in[5];
    const float* W2    = (const float*)d_in[6];
    const float* root2 = (const float*)d_in[7];
    const float* b2    = (const float*)d_in[8];
    float* out = (float*)d_out;

    const int E = in_sizes[2];              // num edges
    const int* src = edge_index;            // edge_index[0]
    const int* dst = edge_index + E;        // edge_index[1]

    int* gbins = (int*)d_ws;
    hipMemsetAsync(gbins, 0, NBINS * sizeof(int), stream);

    rgcn_hist<<<HIST_GRID, HIST_BLOCK, 0, stream>>>(src, dst, edge_type, E, gbins);
    rgcn_finish<<<1, 512, 0, stream>>>(gbins, W1, root1, b1, W2, root2, b2, out);
}